// Round 1
// baseline (544.381 us; speedup 1.0000x reference)
//
#include <hip/hip_runtime.h>

typedef float f32x4 __attribute__((ext_vector_type(4)));
typedef short s16x8 __attribute__((ext_vector_type(8)));
typedef unsigned short us4 __attribute__((ext_vector_type(4)));

#define MFMA16(a, b, c) __builtin_amdgcn_mfma_f32_16x16x32_bf16(a, b, c, 0, 0, 0)

__device__ __forceinline__ unsigned short f2bf(float f) {
    union { float f; unsigned u; } v; v.f = f;
    unsigned r = v.u + 0x7fffu + ((v.u >> 16) & 1u);   // RNE truncate to bf16
    return (unsigned short)(r >> 16);
}

// ---------------------------------------------------------------------------
// Kernel 1: convert x -> bf16 (row-major), W{q,k,v} -> bf16 TRANSPOSED [n][k]
// blocks [0,4096): x, one float4 per thread. blocks [4096,7168): weights.
// ---------------------------------------------------------------------------
__global__ __launch_bounds__(256) void k_convert(
    const float* __restrict__ x, const float* __restrict__ wq,
    const float* __restrict__ wk, const float* __restrict__ wv,
    unsigned short* __restrict__ xbf, unsigned short* __restrict__ wt)
{
    int bid = blockIdx.x, t = threadIdx.x;
    if (bid < 4096) {
        int gid = bid * 256 + t;                 // 1,048,576 float4s = 4,194,304 floats
        float4 v = ((const float4*)x)[gid];
        us4 o = { f2bf(v.x), f2bf(v.y), f2bf(v.z), f2bf(v.w) };
        ((us4*)xbf)[gid] = o;
    } else {
        int idx = (bid - 4096) * 256 + t;        // 786,432 elements
        int w = idx >> 18;                       // which matrix (262144 each)
        int r = idx & 262143;
        int k = r >> 9, n = r & 511;
        const float* src = (w == 0) ? wq : (w == 1) ? wk : wv;
        // wt layout: [w*512 + n][k], k contiguous
        wt[((size_t)(w * 512 + n) << 9) + k] = f2bf(src[r]);
    }
}

// ---------------------------------------------------------------------------
// Kernel 2: bf16 MFMA GEMM: [8192 x 512] @ [512 x 1536] -> Q, K (row-major),
// V transposed [b][d][n]. Block 256 thr = 4 waves as 2x2 of 32x32 tiles.
// Grid (128, 24).
// ---------------------------------------------------------------------------
__global__ __launch_bounds__(256) void k_gemm(
    const unsigned short* __restrict__ xbf, const unsigned short* __restrict__ wt,
    unsigned short* __restrict__ qbf, unsigned short* __restrict__ kbf,
    unsigned short* __restrict__ vtbf)
{
    int t = threadIdx.x;
    int wave = t >> 6, lane = t & 63, c = lane & 15, quad = lane >> 4;
    int m0 = blockIdx.x * 64 + ((wave >> 1) * 32);
    int n0 = blockIdx.y * 64 + ((wave & 1) * 32);

    const unsigned short* a0p = xbf + (size_t)(m0 + c) * 512 + quad * 8;
    const unsigned short* a1p = a0p + 16 * 512;
    const unsigned short* b0p = wt + (size_t)(n0 + c) * 512 + quad * 8;
    const unsigned short* b1p = b0p + 16 * 512;

    f32x4 acc00 = {0.f,0.f,0.f,0.f}, acc01 = {0.f,0.f,0.f,0.f};
    f32x4 acc10 = {0.f,0.f,0.f,0.f}, acc11 = {0.f,0.f,0.f,0.f};

    #pragma unroll 4
    for (int k0 = 0; k0 < 512; k0 += 32) {
        s16x8 a0 = *(const s16x8*)(a0p + k0);
        s16x8 a1 = *(const s16x8*)(a1p + k0);
        s16x8 b0 = *(const s16x8*)(b0p + k0);
        s16x8 b1 = *(const s16x8*)(b1p + k0);
        acc00 = MFMA16(a0, b0, acc00);
        acc01 = MFMA16(a0, b1, acc01);
        acc10 = MFMA16(a1, b0, acc10);
        acc11 = MFMA16(a1, b1, acc11);
    }

    f32x4 av[2][2];
    av[0][0] = acc00; av[0][1] = acc01; av[1][0] = acc10; av[1][1] = acc11;

    #pragma unroll
    for (int mt = 0; mt < 2; mt++) {
        #pragma unroll
        for (int nt = 0; nt < 2; nt++) {
            int col = n0 + nt * 16 + c;          // 0..1535, block-uniform branch below
            #pragma unroll
            for (int r = 0; r < 4; r++) {
                int rw = m0 + mt * 16 + quad * 4 + r;    // global row 0..8191
                unsigned short bf = f2bf(av[mt][nt][r]);
                if (col < 512) {
                    qbf[(size_t)rw * 512 + col] = bf;
                } else if (col < 1024) {
                    kbf[(size_t)rw * 512 + (col - 512)] = bf;
                } else {
                    int bb = rw >> 11, nn = rw & 2047;
                    vtbf[((size_t)(bb * 512 + (col - 1024))) * 2048 + nn] = bf;
                }
            }
        }
    }
}

// ---------------------------------------------------------------------------
// Kernel 3: fused attention. Block = 16 q-rows, 4 waves split 2048 keys
// (512 each). No-max softmax (scores ~N(0,1)). Cross-wave combine via LDS.
// Grid 512.
// ---------------------------------------------------------------------------
__global__ __launch_bounds__(256, 2) void k_attn(
    const unsigned short* __restrict__ qbf, const unsigned short* __restrict__ kbf,
    const unsigned short* __restrict__ vtbf, float* __restrict__ zout)
{
    __shared__ float Ocomb[16 * 512];            // 32 KB
    __shared__ float Lcomb[16];
    __shared__ unsigned short Pst[4][16 * 40];   // per-wave P staging, stride 40 halfwords

    int t = threadIdx.x;
    for (int i = t; i < 16 * 512; i += 256) Ocomb[i] = 0.f;
    if (t < 16) Lcomb[t] = 0.f;
    __syncthreads();

    int wave = t >> 6, lane = t & 63, c = lane & 15, quad = lane >> 4;
    int blk = blockIdx.x;
    int b = blk >> 7;                 // 128 q-blocks per batch
    int q0 = (blk & 127) << 4;

    // Q A-fragments resident: lane reads row (q0+c), k-chunk kk
    const unsigned short* qp = qbf + (size_t)(b * 2048 + q0 + c) * 512 + quad * 8;
    s16x8 qf[16];
    #pragma unroll
    for (int kk = 0; kk < 16; kk++) qf[kk] = *(const s16x8*)(qp + kk * 32);

    f32x4 acc[32];
    #pragma unroll
    for (int dt = 0; dt < 32; dt++) acc[dt] = (f32x4){0.f, 0.f, 0.f, 0.f};
    float lsum[4] = {0.f, 0.f, 0.f, 0.f};

    const float scale = 0.044194173824159216f;   // 1/sqrt(512)
    unsigned short* pst = &Pst[wave][0];
    const unsigned short* vbase = vtbf + (size_t)b * 512 * 2048 + (size_t)c * 2048 + quad * 8;

    for (int kt = 0; kt < 16; kt++) {
        int keybase = wave * 512 + kt * 32;
        const unsigned short* kp0 = kbf + (size_t)(b * 2048 + keybase + c) * 512 + quad * 8;
        const unsigned short* kp1 = kp0 + 16 * 512;

        f32x4 s0 = {0.f,0.f,0.f,0.f}, s1 = {0.f,0.f,0.f,0.f};
        #pragma unroll
        for (int kk = 0; kk < 16; kk++) {
            s16x8 kb0 = *(const s16x8*)(kp0 + kk * 32);
            s16x8 kb1 = *(const s16x8*)(kp1 + kk * 32);
            s0 = MFMA16(qf[kk], kb0, s0);
            s1 = MFMA16(qf[kk], kb1, s1);
        }

        // ensure previous iteration's pa read is done before we overwrite
        asm volatile("s_waitcnt lgkmcnt(0)" ::: "memory");
        #pragma unroll
        for (int r = 0; r < 4; r++) {
            float p0 = __expf(s0[r] * scale);    // score row quad*4+r, key keybase+c
            float p1 = __expf(s1[r] * scale);    // key keybase+16+c
            int row = quad * 4 + r;
            pst[row * 40 + c] = f2bf(p0);
            pst[row * 40 + 16 + c] = f2bf(p1);
            lsum[r] += p0 + p1;
        }
        // ensure writes complete before re-reading in A-layout
        asm volatile("s_waitcnt lgkmcnt(0)" ::: "memory");
        s16x8 pa = *(const s16x8*)(pst + c * 40 + quad * 8);  // A[m=c][k=quad*8+j]

        const unsigned short* vp = vbase + keybase;
        #pragma unroll
        for (int dt = 0; dt < 32; dt++) {
            s16x8 vb = *(const s16x8*)(vp + (size_t)dt * 16 * 2048);
            acc[dt] = MFMA16(pa, vb, acc[dt]);
        }
    }

    // reduce l across the 16 lanes of each quad, add to block accumulator
    #pragma unroll
    for (int r = 0; r < 4; r++) {
        float v = lsum[r];
        v += __shfl_xor(v, 1, 16);
        v += __shfl_xor(v, 2, 16);
        v += __shfl_xor(v, 4, 16);
        v += __shfl_xor(v, 8, 16);
        if (c == 0) atomicAdd(&Lcomb[quad * 4 + r], v);
    }
    // add O partials
    #pragma unroll
    for (int dt = 0; dt < 32; dt++) {
        #pragma unroll
        for (int r = 0; r < 4; r++) {
            atomicAdd(&Ocomb[(quad * 4 + r) * 512 + dt * 16 + c], acc[dt][r]);
        }
    }
    __syncthreads();

    size_t outbase = (size_t)(b * 2048 + q0) * 512;
    for (int i = t; i < 16 * 512; i += 256) {
        int row = i >> 9;
        zout[outbase + i] = Ocomb[i] / Lcomb[row];
    }
}

// ---------------------------------------------------------------------------
// Kernel 4: prior P. One block per (b,i) row: sigma = x_row . Ws, then
// P[j] = exp(-0.5 ((i-j)/sigma)^2) / sum  (inv_norm prefactor cancels).
// Grid 8192. Runs LAST (overwrites the scratch region of d_out).
// ---------------------------------------------------------------------------
__global__ __launch_bounds__(256) void k_prior(
    const float* __restrict__ x, const float* __restrict__ wsv,
    float* __restrict__ pout)
{
    __shared__ float red[4];
    __shared__ float red2[4];

    int blk = blockIdx.x;             // global row 0..8191
    int i = blk & 2047;
    int t = threadIdx.x;
    const float* xr = x + (size_t)blk * 512;

    float part = xr[t] * wsv[t] + xr[t + 256] * wsv[t + 256];
    #pragma unroll
    for (int o = 32; o; o >>= 1) part += __shfl_xor(part, o, 64);
    if ((t & 63) == 0) red[t >> 6] = part;
    __syncthreads();
    float sigma = red[0] + red[1] + red[2] + red[3];

    float inv2 = 0.5f / (sigma * sigma);
    float g[8];
    float sum = 0.f;
    #pragma unroll
    for (int u = 0; u < 8; u++) {
        int j = t + u * 256;
        float d = (float)(j - i);
        g[u] = (j == i) ? 1.0f : __expf(-(d * d) * inv2);
        sum += g[u];
    }
    #pragma unroll
    for (int o = 32; o; o >>= 1) sum += __shfl_xor(sum, o, 64);
    if ((t & 63) == 0) red2[t >> 6] = sum;
    __syncthreads();
    float inv = 1.0f / (red2[0] + red2[1] + red2[2] + red2[3]);

    float* pr = pout + (size_t)blk * 2048;
    #pragma unroll
    for (int u = 0; u < 8; u++) pr[t + u * 256] = g[u] * inv;
}

// ---------------------------------------------------------------------------
extern "C" void kernel_launch(void* const* d_in, const int* in_sizes, int n_in,
                              void* d_out, int out_size, void* d_ws, size_t ws_size,
                              hipStream_t stream)
{
    const float* x  = (const float*)d_in[0];
    const float* wq = (const float*)d_in[1];
    const float* wk = (const float*)d_in[2];
    const float* wv = (const float*)d_in[3];
    const float* ws = (const float*)d_in[4];

    float* zout = (float*)d_out;                       // (4,2048,512) = 4,194,304 floats
    float* pout = zout + (size_t)4 * 2048 * 512;       // (4,2048,2048) = 16,777,216 floats

    // Scratch placed inside the P output region (written last by k_prior):
    // needs 18,350,080 ushorts = 36.7 MB <= 67.1 MB available.
    unsigned short* scratch = (unsigned short*)pout;
    unsigned short* xbf  = scratch;                    // 4,194,304
    unsigned short* wt   = xbf  + (size_t)4194304;     //   786,432 (Wq^T|Wk^T|Wv^T, [n][k])
    unsigned short* qbf  = wt   + (size_t)786432;      // 4,194,304
    unsigned short* kbf  = qbf  + (size_t)4194304;     // 4,194,304
    unsigned short* vtbf = kbf  + (size_t)4194304;     // 4,194,304 ([b][d][n])

    k_convert<<<dim3(7168), dim3(256), 0, stream>>>(x, wq, wk, wv, xbf, wt);
    k_gemm<<<dim3(128, 24), dim3(256), 0, stream>>>(xbf, wt, qbf, kbf, vtbf);
    k_attn<<<dim3(512), dim3(256), 0, stream>>>(qbf, kbf, vtbf, zout);
    k_prior<<<dim3(8192), dim3(256), 0, stream>>>(x, ws, pout);
}

// Round 2
// 437.119 us; speedup vs baseline: 1.2454x; 1.2454x over previous
//
#include <hip/hip_runtime.h>

typedef float f32x4 __attribute__((ext_vector_type(4)));
typedef short s16x8 __attribute__((ext_vector_type(8)));
typedef unsigned short us4 __attribute__((ext_vector_type(4)));

#define MFMA16(a, b, c) __builtin_amdgcn_mfma_f32_16x16x32_bf16(a, b, c, 0, 0, 0)

__device__ __forceinline__ unsigned short f2bf(float f) {
    union { float f; unsigned u; } v; v.f = f;
    unsigned r = v.u + 0x7fffu + ((v.u >> 16) & 1u);   // RNE truncate to bf16
    return (unsigned short)(r >> 16);
}

// ---------------------------------------------------------------------------
// Kernel 1: convert x -> bf16 (row-major), W{q,k,v} -> bf16 TRANSPOSED [n][k]
// ---------------------------------------------------------------------------
__global__ __launch_bounds__(256) void k_convert(
    const float* __restrict__ x, const float* __restrict__ wq,
    const float* __restrict__ wk, const float* __restrict__ wv,
    unsigned short* __restrict__ xbf, unsigned short* __restrict__ wt)
{
    int bid = blockIdx.x, t = threadIdx.x;
    if (bid < 4096) {
        int gid = bid * 256 + t;
        float4 v = ((const float4*)x)[gid];
        us4 o = { f2bf(v.x), f2bf(v.y), f2bf(v.z), f2bf(v.w) };
        ((us4*)xbf)[gid] = o;
    } else {
        int idx = (bid - 4096) * 256 + t;
        int w = idx >> 18;
        int r = idx & 262143;
        int k = r >> 9, n = r & 511;
        const float* src = (w == 0) ? wq : (w == 1) ? wk : wv;
        wt[((size_t)(w * 512 + n) << 9) + k] = f2bf(src[r]);
    }
}

// ---------------------------------------------------------------------------
// Kernel 2: bf16 MFMA GEMM: [8192 x 512] @ [512 x 1536] -> Q, K (row-major),
// V transposed [b][d][n]. Block 256 thr = 4 waves as 2x2 of 32x32 tiles.
// ---------------------------------------------------------------------------
__global__ __launch_bounds__(256) void k_gemm(
    const unsigned short* __restrict__ xbf, const unsigned short* __restrict__ wt,
    unsigned short* __restrict__ qbf, unsigned short* __restrict__ kbf,
    unsigned short* __restrict__ vtbf)
{
    int t = threadIdx.x;
    int wave = t >> 6, lane = t & 63, c = lane & 15, quad = lane >> 4;
    int m0 = blockIdx.x * 64 + ((wave >> 1) * 32);
    int n0 = blockIdx.y * 64 + ((wave & 1) * 32);

    const unsigned short* a0p = xbf + (size_t)(m0 + c) * 512 + quad * 8;
    const unsigned short* a1p = a0p + 16 * 512;
    const unsigned short* b0p = wt + (size_t)(n0 + c) * 512 + quad * 8;
    const unsigned short* b1p = b0p + 16 * 512;

    f32x4 acc00 = {0.f,0.f,0.f,0.f}, acc01 = {0.f,0.f,0.f,0.f};
    f32x4 acc10 = {0.f,0.f,0.f,0.f}, acc11 = {0.f,0.f,0.f,0.f};

    #pragma unroll 4
    for (int k0 = 0; k0 < 512; k0 += 32) {
        s16x8 a0 = *(const s16x8*)(a0p + k0);
        s16x8 a1 = *(const s16x8*)(a1p + k0);
        s16x8 b0 = *(const s16x8*)(b0p + k0);
        s16x8 b1 = *(const s16x8*)(b1p + k0);
        acc00 = MFMA16(a0, b0, acc00);
        acc01 = MFMA16(a0, b1, acc01);
        acc10 = MFMA16(a1, b0, acc10);
        acc11 = MFMA16(a1, b1, acc11);
    }

    f32x4 av[2][2];
    av[0][0] = acc00; av[0][1] = acc01; av[1][0] = acc10; av[1][1] = acc11;

    #pragma unroll
    for (int mt = 0; mt < 2; mt++) {
        #pragma unroll
        for (int nt = 0; nt < 2; nt++) {
            int col = n0 + nt * 16 + c;
            #pragma unroll
            for (int r = 0; r < 4; r++) {
                int rw = m0 + mt * 16 + quad * 4 + r;
                unsigned short bf = f2bf(av[mt][nt][r]);
                if (col < 512) {
                    qbf[(size_t)rw * 512 + col] = bf;
                } else if (col < 1024) {
                    kbf[(size_t)rw * 512 + (col - 512)] = bf;
                } else {
                    int bb = rw >> 11, nn = rw & 2047;
                    vtbf[((size_t)(bb * 512 + (col - 1024))) * 2048 + nn] = bf;
                }
            }
        }
    }
}

// ---------------------------------------------------------------------------
// Kernel 3: fused attention, two-phase.
// Block = 512 thr (8 waves), 16 q-rows per block, grid 512 (2 blocks/CU).
// Phase A: waves split 2048 keys (256 each): S=QK^T, exp -> P (bf16) to LDS,
//          l accumulated via quad-shuffle + LDS atomic (128 atomics/block).
// Phase B: waves split d (64 dims each): O = P@V with acc[4] only (16 regs),
//          each wave owns its output slice -> direct global store, no combine.
// launch_bounds(512,4) caps regs at 128/wave -> 16 waves/CU occupancy.
// ---------------------------------------------------------------------------
__global__ __launch_bounds__(512, 4) void k_attn(
    const unsigned short* __restrict__ qbf, const unsigned short* __restrict__ kbf,
    const unsigned short* __restrict__ vtbf, float* __restrict__ zout)
{
    constexpr int RP = 2056;                       // row stride, +8 pad (16B-aligned)
    __shared__ __align__(16) unsigned short Pls[16 * RP];   // 65792 B
    __shared__ float Lcomb[16];

    int t = threadIdx.x;
    int wave = t >> 6, lane = t & 63, c = lane & 15, quad = lane >> 4;
    int blk = blockIdx.x;
    int b = blk >> 7;                 // 128 q-blocks per batch
    int q0 = (blk & 127) << 4;

    if (t < 16) Lcomb[t] = 0.f;
    __syncthreads();

    // -------- Phase A: scores + exp, keys [wave*256, wave*256+256) --------
    const unsigned short* qp = qbf + (size_t)(b * 2048 + q0 + c) * 512 + quad * 8;
    s16x8 qf[16];
    #pragma unroll
    for (int kk = 0; kk < 16; kk++) qf[kk] = *(const s16x8*)(qp + kk * 32);

    float lsum[4] = {0.f, 0.f, 0.f, 0.f};
    const float scale = 0.044194173824159216f;     // 1/sqrt(512)

    for (int kt = 0; kt < 8; kt++) {
        int keybase = wave * 256 + kt * 32;
        const unsigned short* kp0 = kbf + (size_t)(b * 2048 + keybase + c) * 512 + quad * 8;
        const unsigned short* kp1 = kp0 + 16 * 512;

        f32x4 s0 = {0.f,0.f,0.f,0.f}, s1 = {0.f,0.f,0.f,0.f};
        #pragma unroll
        for (int kk = 0; kk < 16; kk++) {
            s16x8 kb0 = *(const s16x8*)(kp0 + kk * 32);
            s16x8 kb1 = *(const s16x8*)(kp1 + kk * 32);
            s0 = MFMA16(qf[kk], kb0, s0);
            s1 = MFMA16(qf[kk], kb1, s1);
        }

        #pragma unroll
        for (int r = 0; r < 4; r++) {
            float p0 = __expf(s0[r] * scale);      // key keybase+c
            float p1 = __expf(s1[r] * scale);      // key keybase+16+c
            int row = quad * 4 + r;
            Pls[row * RP + keybase + c] = f2bf(p0);
            Pls[row * RP + keybase + 16 + c] = f2bf(p1);
            lsum[r] += p0 + p1;
        }
    }

    #pragma unroll
    for (int r = 0; r < 4; r++) {
        float v = lsum[r];
        v += __shfl_xor(v, 1, 16);
        v += __shfl_xor(v, 2, 16);
        v += __shfl_xor(v, 4, 16);
        v += __shfl_xor(v, 8, 16);
        if (c == 0) atomicAdd(&Lcomb[quad * 4 + r], v);
    }
    __syncthreads();   // P complete + l complete

    // -------- Phase B: O = P @ V, dims [wave*64, wave*64+64) --------
    int d0 = wave * 64;
    f32x4 acc[4];
    #pragma unroll
    for (int dt = 0; dt < 4; dt++) acc[dt] = (f32x4){0.f, 0.f, 0.f, 0.f};

    const unsigned short* vbase =
        vtbf + (size_t)b * 512 * 2048 + (size_t)(d0 + c) * 2048 + quad * 8;
    const unsigned short* pbase = Pls + (size_t)c * RP + quad * 8;

    #pragma unroll 4
    for (int kc = 0; kc < 64; kc++) {
        s16x8 pa = *(const s16x8*)(pbase + kc * 32);     // A[m=c][k=kc*32+quad*8+j]
        #pragma unroll
        for (int dt = 0; dt < 4; dt++) {
            s16x8 vb = *(const s16x8*)(vbase + (size_t)dt * 16 * 2048 + kc * 32);
            acc[dt] = MFMA16(pa, vb, acc[dt]);
        }
    }

    size_t outrow = (size_t)(b * 2048 + q0);
    #pragma unroll
    for (int r = 0; r < 4; r++) {
        int row = quad * 4 + r;
        float inv = 1.0f / Lcomb[row];
        #pragma unroll
        for (int dt = 0; dt < 4; dt++) {
            zout[(outrow + row) * 512 + d0 + dt * 16 + c] = acc[dt][r] * inv;
        }
    }
}

// ---------------------------------------------------------------------------
// Kernel 4: prior P. One block per (b,i) row. inv_norm prefactor cancels in
// row normalization. Runs LAST (overwrites the scratch region of d_out).
// ---------------------------------------------------------------------------
__global__ __launch_bounds__(256) void k_prior(
    const float* __restrict__ x, const float* __restrict__ wsv,
    float* __restrict__ pout)
{
    __shared__ float red[4];
    __shared__ float red2[4];

    int blk = blockIdx.x;             // global row 0..8191
    int i = blk & 2047;
    int t = threadIdx.x;
    const float* xr = x + (size_t)blk * 512;

    float part = xr[t] * wsv[t] + xr[t + 256] * wsv[t + 256];
    #pragma unroll
    for (int o = 32; o; o >>= 1) part += __shfl_xor(part, o, 64);
    if ((t & 63) == 0) red[t >> 6] = part;
    __syncthreads();
    float sigma = red[0] + red[1] + red[2] + red[3];

    float inv2 = 0.5f / (sigma * sigma);
    float g[8];
    float sum = 0.f;
    #pragma unroll
    for (int u = 0; u < 8; u++) {
        int j = t + u * 256;
        float d = (float)(j - i);
        g[u] = (j == i) ? 1.0f : __expf(-(d * d) * inv2);
        sum += g[u];
    }
    #pragma unroll
    for (int o = 32; o; o >>= 1) sum += __shfl_xor(sum, o, 64);
    if ((t & 63) == 0) red2[t >> 6] = sum;
    __syncthreads();
    float inv = 1.0f / (red2[0] + red2[1] + red2[2] + red2[3]);

    float* pr = pout + (size_t)blk * 2048;
    #pragma unroll
    for (int u = 0; u < 8; u++) pr[t + u * 256] = g[u] * inv;
}

// ---------------------------------------------------------------------------
extern "C" void kernel_launch(void* const* d_in, const int* in_sizes, int n_in,
                              void* d_out, int out_size, void* d_ws, size_t ws_size,
                              hipStream_t stream)
{
    const float* x  = (const float*)d_in[0];
    const float* wq = (const float*)d_in[1];
    const float* wk = (const float*)d_in[2];
    const float* wv = (const float*)d_in[3];
    const float* ws = (const float*)d_in[4];

    float* zout = (float*)d_out;                       // (4,2048,512)
    float* pout = zout + (size_t)4 * 2048 * 512;       // (4,2048,2048)

    // Scratch inside the P output region (written last by k_prior):
    // 18,350,080 ushorts = 36.7 MB <= 67.1 MB available.
    unsigned short* scratch = (unsigned short*)pout;
    unsigned short* xbf  = scratch;                    // 4,194,304
    unsigned short* wt   = xbf  + (size_t)4194304;     //   786,432
    unsigned short* qbf  = wt   + (size_t)786432;      // 4,194,304
    unsigned short* kbf  = qbf  + (size_t)4194304;     // 4,194,304
    unsigned short* vtbf = kbf  + (size_t)4194304;     // 4,194,304 ([b][d][n])

    k_convert<<<dim3(7168), dim3(256), 0, stream>>>(x, wq, wk, wv, xbf, wt);
    k_gemm<<<dim3(128, 24), dim3(256), 0, stream>>>(xbf, wt, qbf, kbf, vtbf);
    k_attn<<<dim3(512), dim3(512), 0, stream>>>(qbf, kbf, vtbf, zout);
    k_prior<<<dim3(8192), dim3(256), 0, stream>>>(x, ws, pout);
}

// Round 3
// 213.555 us; speedup vs baseline: 2.5491x; 2.0469x over previous
//
#include <hip/hip_runtime.h>

typedef float f32x4 __attribute__((ext_vector_type(4)));
typedef short s16x8 __attribute__((ext_vector_type(8)));
typedef unsigned short us4 __attribute__((ext_vector_type(4)));

#define MFMA16(a, b, c) __builtin_amdgcn_mfma_f32_16x16x32_bf16(a, b, c, 0, 0, 0)

// async global->LDS DMA, 16B per lane. LDS dest must be wave-uniform base + lane*16.
#define GLOAD_LDS16(gp, lp) __builtin_amdgcn_global_load_lds( \
    (__attribute__((address_space(1))) void*)(gp),            \
    (__attribute__((address_space(3))) void*)(lp), 16, 0, 0)

__device__ __forceinline__ unsigned short f2bf(float f) {
    union { float f; unsigned u; } v; v.f = f;
    unsigned r = v.u + 0x7fffu + ((v.u >> 16) & 1u);   // RNE truncate to bf16
    return (unsigned short)(r >> 16);
}

// ---------------------------------------------------------------------------
// m97-style GEMM core: C[128x128] += A[128xK] @ B[128xK]^T (both row-major,
// contraction contiguous). 256 threads = 4 waves in 2x2 quadrants of 64x64,
// each wave 4x4 tiles of 16x16x32 MFMA. LDS tiles As/Bs: [128][32] bf16, no
// pad (global_load_lds requires linear layout; ds_read_b128 pattern is
// conflict-free service groups: addr mod 128 = 16*((c+quad*?)..) spans all
// 32 banks per 8-lane group).
// ---------------------------------------------------------------------------
__device__ __forceinline__ void gemm_core(
    const unsigned short* __restrict__ Ab, size_t Astride,
    const unsigned short* __restrict__ Bb, size_t Bstride,
    int K, unsigned short* As, unsigned short* Bs,
    int t, f32x4 acc[4][4])
{
    const int wave = t >> 6, lane = t & 63;
    const int c = lane & 15, quad = lane >> 4;
    const int wm = (wave >> 1) * 64, wn = (wave & 1) * 64;
    const int srow = t >> 2;            // staging row 0..63 (+64 for 2nd inst)
    const int scol = (t & 3) * 8;       // staging col chunk (8 elts = 16B)

    for (int k0 = 0; k0 < K; k0 += 32) {
        __syncthreads();                // prev iteration's ds_reads done
        const unsigned short* ga = Ab + (size_t)srow * Astride + k0 + scol;
        const unsigned short* gb = Bb + (size_t)srow * Bstride + k0 + scol;
        GLOAD_LDS16(ga,                 As + t * 8);
        GLOAD_LDS16(ga + 64 * Astride,  As + 2048 + t * 8);
        GLOAD_LDS16(gb,                 Bs + t * 8);
        GLOAD_LDS16(gb + 64 * Bstride,  Bs + 2048 + t * 8);
        __syncthreads();                // vmcnt(0) drain inserted by compiler

        s16x8 af[4], bf[4];
        #pragma unroll
        for (int i = 0; i < 4; i++)
            af[i] = *(const s16x8*)(As + (wm + i * 16 + c) * 32 + quad * 8);
        #pragma unroll
        for (int i = 0; i < 4; i++)
            bf[i] = *(const s16x8*)(Bs + (wn + i * 16 + c) * 32 + quad * 8);
        #pragma unroll
        for (int mt = 0; mt < 4; mt++)
            #pragma unroll
            for (int nt = 0; nt < 4; nt++)
                acc[mt][nt] = MFMA16(af[mt], bf[nt], acc[mt][nt]);
    }
}

// ---------------------------------------------------------------------------
// Kernel 1: convert x -> bf16 row-major; W{q,k,v} -> bf16 transposed [n][k];
// zero the l accumulator (workspace is re-poisoned 0xAA before every launch).
// ---------------------------------------------------------------------------
__global__ __launch_bounds__(256) void k_convert(
    const float* __restrict__ x, const float* __restrict__ wq,
    const float* __restrict__ wk, const float* __restrict__ wv,
    unsigned short* __restrict__ xbf, unsigned short* __restrict__ wt,
    float* __restrict__ lg)
{
    int bid = blockIdx.x, t = threadIdx.x;
    if (bid < 4096) {
        int gid = bid * 256 + t;
        float4 v = ((const float4*)x)[gid];
        us4 o = { f2bf(v.x), f2bf(v.y), f2bf(v.z), f2bf(v.w) };
        ((us4*)xbf)[gid] = o;
    } else if (bid < 7168) {
        int idx = (bid - 4096) * 256 + t;
        int w = idx >> 18;
        int r = idx & 262143;
        int k = r >> 9, n = r & 511;
        const float* src = (w == 0) ? wq : (w == 1) ? wk : wv;
        wt[((size_t)(w * 512 + n) << 9) + k] = f2bf(src[r]);
    } else {
        lg[(bid - 7168) * 256 + t] = 0.f;
    }
}

// ---------------------------------------------------------------------------
// Kernel 2: QKV projection. [8192x512] @ [1536x512]^T. Grid (64,12).
// blockIdx.y: 0-3 -> Q, 4-7 -> K, 8-11 -> V (V stored transposed [b][d][n],
// packed 4-row 8B stores).
// ---------------------------------------------------------------------------
__global__ __launch_bounds__(256) void k_proj(
    const unsigned short* __restrict__ xbf, const unsigned short* __restrict__ wt,
    unsigned short* __restrict__ qbf, unsigned short* __restrict__ kbf,
    unsigned short* __restrict__ vtbf)
{
    __shared__ __align__(16) unsigned short As[128 * 32];
    __shared__ __align__(16) unsigned short Bs[128 * 32];

    int t = threadIdx.x;
    int m0 = blockIdx.x * 128, n0 = blockIdx.y * 128;
    f32x4 acc[4][4] = {};

    gemm_core(xbf + (size_t)m0 * 512, 512, wt + (size_t)n0 * 512, 512,
              512, As, Bs, t, acc);

    int wave = t >> 6, lane = t & 63, c = lane & 15, quad = lane >> 4;
    int wm = (wave >> 1) * 64, wn = (wave & 1) * 64;
    int sel = blockIdx.y >> 2;                    // 0=q 1=k 2=v (block-uniform)

    if (sel < 2) {
        unsigned short* dst = sel ? kbf : qbf;
        int ncol0 = n0 - sel * 512;
        #pragma unroll
        for (int mt = 0; mt < 4; mt++) {
            #pragma unroll
            for (int nt = 0; nt < 4; nt++) {
                int col = ncol0 + wn + nt * 16 + c;
                #pragma unroll
                for (int r = 0; r < 4; r++) {
                    int rw = m0 + wm + mt * 16 + quad * 4 + r;
                    dst[(size_t)rw * 512 + col] = f2bf(acc[mt][nt][r]);
                }
            }
        }
    } else {
        #pragma unroll
        for (int mt = 0; mt < 4; mt++) {
            int rw0 = m0 + wm + mt * 16 + quad * 4;      // 4 consecutive rows
            int bb = rw0 >> 11, nn = rw0 & 2047;
            #pragma unroll
            for (int nt = 0; nt < 4; nt++) {
                int d = (n0 - 1024) + wn + nt * 16 + c;
                us4 pk = { f2bf(acc[mt][nt][0]), f2bf(acc[mt][nt][1]),
                           f2bf(acc[mt][nt][2]), f2bf(acc[mt][nt][3]) };
                *(us4*)(vtbf + ((size_t)(bb * 512 + d)) * 2048 + nn) = pk;
            }
        }
    }
}

// ---------------------------------------------------------------------------
// Kernel 3: scores. Per batch: S = Q @ K^T, P = exp(S*scale) -> bf16 scratch,
// l[q] += row-sums (quad shuffle-reduce + global atomicAdd). Grid (16,16,4).
// No max-subtraction: scores ~N(0,1), exp is safe in f32.
// ---------------------------------------------------------------------------
__global__ __launch_bounds__(256) void k_score(
    const unsigned short* __restrict__ qbf, const unsigned short* __restrict__ kbf,
    unsigned short* __restrict__ pbf, float* __restrict__ lg)
{
    __shared__ __align__(16) unsigned short As[128 * 32];
    __shared__ __align__(16) unsigned short Bs[128 * 32];

    int t = threadIdx.x;
    int b = blockIdx.z;
    int m0 = blockIdx.x * 128, n0 = blockIdx.y * 128;
    f32x4 acc[4][4] = {};

    gemm_core(qbf + (size_t)(b * 2048 + m0) * 512, 512,
              kbf + (size_t)(b * 2048 + n0) * 512, 512,
              512, As, Bs, t, acc);

    int wave = t >> 6, lane = t & 63, c = lane & 15, quad = lane >> 4;
    int wm = (wave >> 1) * 64, wn = (wave & 1) * 64;
    const float scale = 0.044194173824159216f;    // 1/sqrt(512)

    #pragma unroll
    for (int mt = 0; mt < 4; mt++) {
        #pragma unroll
        for (int r = 0; r < 4; r++) {
            int row = m0 + wm + mt * 16 + quad * 4 + r;
            float rs = 0.f;
            #pragma unroll
            for (int nt = 0; nt < 4; nt++) {
                float p = __expf(acc[mt][nt][r] * scale);
                rs += p;
                pbf[(size_t)(b * 2048 + row) * 2048 + n0 + wn + nt * 16 + c] = f2bf(p);
            }
            rs += __shfl_xor(rs, 1, 16);
            rs += __shfl_xor(rs, 2, 16);
            rs += __shfl_xor(rs, 4, 16);
            rs += __shfl_xor(rs, 8, 16);
            if (c == 0) atomicAdd(&lg[b * 2048 + row], rs);
        }
    }
}

// ---------------------------------------------------------------------------
// Kernel 4: output. Per batch: O = P @ Vt^T (Vt is [d][n], contraction over
// keys contiguous for both operands), scaled by 1/l. Grid (16,4,4).
// ---------------------------------------------------------------------------
__global__ __launch_bounds__(256) void k_out(
    const unsigned short* __restrict__ pbf, const unsigned short* __restrict__ vtbf,
    const float* __restrict__ lg, float* __restrict__ zout)
{
    __shared__ __align__(16) unsigned short As[128 * 32];
    __shared__ __align__(16) unsigned short Bs[128 * 32];
    __shared__ float invl[128];

    int t = threadIdx.x;
    int b = blockIdx.z;
    int m0 = blockIdx.x * 128, n0 = blockIdx.y * 128;

    if (t < 128) invl[t] = 1.0f / lg[b * 2048 + m0 + t];

    f32x4 acc[4][4] = {};
    gemm_core(pbf + (size_t)(b * 2048 + m0) * 2048, 2048,
              vtbf + (size_t)(b * 512 + n0) * 2048, 2048,
              2048, As, Bs, t, acc);

    int wave = t >> 6, lane = t & 63, c = lane & 15, quad = lane >> 4;
    int wm = (wave >> 1) * 64, wn = (wave & 1) * 64;

    #pragma unroll
    for (int mt = 0; mt < 4; mt++) {
        #pragma unroll
        for (int nt = 0; nt < 4; nt++) {
            #pragma unroll
            for (int r = 0; r < 4; r++) {
                int row = wm + mt * 16 + quad * 4 + r;
                zout[(size_t)(b * 2048 + m0 + row) * 512 + n0 + wn + nt * 16 + c]
                    = acc[mt][nt][r] * invl[row];
            }
        }
    }
}

// ---------------------------------------------------------------------------
// Kernel 5: prior P. One block per (b,i) row. inv_norm prefactor cancels in
// row normalization. Runs LAST (overwrites all scratch in the P region).
// ---------------------------------------------------------------------------
__global__ __launch_bounds__(256) void k_prior(
    const float* __restrict__ x, const float* __restrict__ wsv,
    float* __restrict__ pout)
{
    __shared__ float red[4];
    __shared__ float red2[4];

    int blk = blockIdx.x;             // global row 0..8191
    int i = blk & 2047;
    int t = threadIdx.x;
    const float* xr = x + (size_t)blk * 512;

    float part = xr[t] * wsv[t] + xr[t + 256] * wsv[t + 256];
    #pragma unroll
    for (int o = 32; o; o >>= 1) part += __shfl_xor(part, o, 64);
    if ((t & 63) == 0) red[t >> 6] = part;
    __syncthreads();
    float sigma = red[0] + red[1] + red[2] + red[3];

    float inv2 = 0.5f / (sigma * sigma);
    float g[8];
    float sum = 0.f;
    #pragma unroll
    for (int u = 0; u < 8; u++) {
        int j = t + u * 256;
        float d = (float)(j - i);
        g[u] = (j == i) ? 1.0f : __expf(-(d * d) * inv2);
        sum += g[u];
    }
    #pragma unroll
    for (int o = 32; o; o >>= 1) sum += __shfl_xor(sum, o, 64);
    if ((t & 63) == 0) red2[t >> 6] = sum;
    __syncthreads();
    float inv = 1.0f / (red2[0] + red2[1] + red2[2] + red2[3]);

    float* pr = pout + (size_t)blk * 2048;
    #pragma unroll
    for (int u = 0; u < 8; u++) pr[t + u * 256] = g[u] * inv;
}

// ---------------------------------------------------------------------------
extern "C" void kernel_launch(void* const* d_in, const int* in_sizes, int n_in,
                              void* d_out, int out_size, void* d_ws, size_t ws_size,
                              hipStream_t stream)
{
    const float* x  = (const float*)d_in[0];
    const float* wq = (const float*)d_in[1];
    const float* wk = (const float*)d_in[2];
    const float* wv = (const float*)d_in[3];
    const float* ws = (const float*)d_in[4];

    float* zout = (float*)d_out;                       // (4,2048,512)
    float* pout = zout + (size_t)4 * 2048 * 512;       // (4,2048,2048) = 67.1 MB

    // Scratch inside the P output region (k_prior overwrites it LAST).
    // Lifetimes: xbf/wt dead after k_proj -> pbf may overlap them.
    // Live peak (k_score): pbf + qbf + kbf + vtbf + lg = 58.75 MB <= 67.1 MB.
    unsigned short* base = (unsigned short*)pout;
    unsigned short* pbf  = base;                        // 16,777,216 (33.5 MB)
    unsigned short* qbf  = base + (size_t)16777216;     //  4,194,304
    unsigned short* kbf  = qbf  + (size_t)4194304;      //  4,194,304
    unsigned short* vtbf = kbf  + (size_t)4194304;      //  4,194,304 ([b][d][n])
    float*          lg   = (float*)(vtbf + (size_t)4194304);   // 8192 f32
    unsigned short* xbf  = base;                        // overlaps pbf (ok)
    unsigned short* wt   = base + (size_t)4194304;      // overlaps pbf (ok)

    k_convert<<<dim3(7200), dim3(256), 0, stream>>>(x, wq, wk, wv, xbf, wt, lg);
    k_proj  <<<dim3(64, 12),    dim3(256), 0, stream>>>(xbf, wt, qbf, kbf, vtbf);
    k_score <<<dim3(16, 16, 4), dim3(256), 0, stream>>>(qbf, kbf, pbf, lg);
    k_out   <<<dim3(16, 4, 4),  dim3(256), 0, stream>>>(pbf, vtbf, lg, zout);
    k_prior <<<dim3(8192),      dim3(256), 0, stream>>>(x, ws, pout);
}

// Round 4
// 208.063 us; speedup vs baseline: 2.6164x; 1.0264x over previous
//
#include <hip/hip_runtime.h>

typedef float f32x4 __attribute__((ext_vector_type(4)));
typedef short s16x8 __attribute__((ext_vector_type(8)));
typedef unsigned short us4 __attribute__((ext_vector_type(4)));

#define MFMA16(a, b, c) __builtin_amdgcn_mfma_f32_16x16x32_bf16(a, b, c, 0, 0, 0)

// async global->LDS DMA, 16B per lane. LDS dest must be wave-uniform base + lane*16.
#define GLOAD_LDS16(gp, lp) __builtin_amdgcn_global_load_lds( \
    (__attribute__((address_space(1))) void*)(gp),            \
    (__attribute__((address_space(3))) void*)(lp), 16, 0, 0)

__device__ __forceinline__ unsigned short f2bf(float f) {
    union { float f; unsigned u; } v; v.f = f;
    unsigned r = v.u + 0x7fffu + ((v.u >> 16) & 1u);   // RNE truncate to bf16
    return (unsigned short)(r >> 16);
}

// ---------------------------------------------------------------------------
// m97-style GEMM core, 128x128 tile: C += A[128xK] @ B[128xK]^T.
// 256 thr = 4 waves in 2x2 quadrants of 64x64, each wave 4x4 16x16x32 MFMAs.
// ---------------------------------------------------------------------------
__device__ __forceinline__ void gemm_core128(
    const unsigned short* __restrict__ Ab, size_t Astride,
    const unsigned short* __restrict__ Bb, size_t Bstride,
    int K, unsigned short* As, unsigned short* Bs,
    int t, f32x4 acc[4][4])
{
    const int wave = t >> 6, lane = t & 63;
    const int c = lane & 15, quad = lane >> 4;
    const int wm = (wave >> 1) * 64, wn = (wave & 1) * 64;
    const int srow = t >> 2;
    const int scol = (t & 3) * 8;

    for (int k0 = 0; k0 < K; k0 += 32) {
        __syncthreads();
        const unsigned short* ga = Ab + (size_t)srow * Astride + k0 + scol;
        const unsigned short* gb = Bb + (size_t)srow * Bstride + k0 + scol;
        GLOAD_LDS16(ga,                 As + t * 8);
        GLOAD_LDS16(ga + 64 * Astride,  As + 2048 + t * 8);
        GLOAD_LDS16(gb,                 Bs + t * 8);
        GLOAD_LDS16(gb + 64 * Bstride,  Bs + 2048 + t * 8);
        __syncthreads();

        s16x8 af[4], bf[4];
        #pragma unroll
        for (int i = 0; i < 4; i++)
            af[i] = *(const s16x8*)(As + (wm + i * 16 + c) * 32 + quad * 8);
        #pragma unroll
        for (int i = 0; i < 4; i++)
            bf[i] = *(const s16x8*)(Bs + (wn + i * 16 + c) * 32 + quad * 8);
        #pragma unroll
        for (int mt = 0; mt < 4; mt++)
            #pragma unroll
            for (int nt = 0; nt < 4; nt++)
                acc[mt][nt] = MFMA16(af[mt], bf[nt], acc[mt][nt]);
    }
}

// ---------------------------------------------------------------------------
// Kernel 1: convert x -> bf16 row-major; W{q,k,v} -> bf16 transposed [n][k];
// zero the l accumulator.
// ---------------------------------------------------------------------------
__global__ __launch_bounds__(256) void k_convert(
    const float* __restrict__ x, const float* __restrict__ wq,
    const float* __restrict__ wk, const float* __restrict__ wv,
    unsigned short* __restrict__ xbf, unsigned short* __restrict__ wt,
    float* __restrict__ lg)
{
    int bid = blockIdx.x, t = threadIdx.x;
    if (bid < 4096) {
        int gid = bid * 256 + t;
        float4 v = ((const float4*)x)[gid];
        us4 o = { f2bf(v.x), f2bf(v.y), f2bf(v.z), f2bf(v.w) };
        ((us4*)xbf)[gid] = o;
    } else if (bid < 7168) {
        int idx = (bid - 4096) * 256 + t;
        int w = idx >> 18;
        int r = idx & 262143;
        int k = r >> 9, n = r & 511;
        const float* src = (w == 0) ? wq : (w == 1) ? wk : wv;
        wt[((size_t)(w * 512 + n) << 9) + k] = f2bf(src[r]);
    } else {
        lg[(bid - 7168) * 256 + t] = 0.f;
    }
}

// ---------------------------------------------------------------------------
// Kernel 2: QKV projection. [8192x512] @ [1536x512]^T. Grid (64,12).
// ---------------------------------------------------------------------------
__global__ __launch_bounds__(256) void k_proj(
    const unsigned short* __restrict__ xbf, const unsigned short* __restrict__ wt,
    unsigned short* __restrict__ qbf, unsigned short* __restrict__ kbf,
    unsigned short* __restrict__ vtbf)
{
    __shared__ __align__(16) unsigned short As[128 * 32];
    __shared__ __align__(16) unsigned short Bs[128 * 32];

    int t = threadIdx.x;
    int m0 = blockIdx.x * 128, n0 = blockIdx.y * 128;
    f32x4 acc[4][4] = {};

    gemm_core128(xbf + (size_t)m0 * 512, 512, wt + (size_t)n0 * 512, 512,
                 512, As, Bs, t, acc);

    int wave = t >> 6, lane = t & 63, c = lane & 15, quad = lane >> 4;
    int wm = (wave >> 1) * 64, wn = (wave & 1) * 64;
    int sel = blockIdx.y >> 2;                    // 0=q 1=k 2=v

    if (sel < 2) {
        unsigned short* dst = sel ? kbf : qbf;
        int ncol0 = n0 - sel * 512;
        #pragma unroll
        for (int mt = 0; mt < 4; mt++) {
            #pragma unroll
            for (int nt = 0; nt < 4; nt++) {
                int col = ncol0 + wn + nt * 16 + c;
                #pragma unroll
                for (int r = 0; r < 4; r++) {
                    int rw = m0 + wm + mt * 16 + quad * 4 + r;
                    dst[(size_t)rw * 512 + col] = f2bf(acc[mt][nt][r]);
                }
            }
        }
    } else {
        #pragma unroll
        for (int mt = 0; mt < 4; mt++) {
            int rw0 = m0 + wm + mt * 16 + quad * 4;
            int bb = rw0 >> 11, nn = rw0 & 2047;
            #pragma unroll
            for (int nt = 0; nt < 4; nt++) {
                int d = (n0 - 1024) + wn + nt * 16 + c;
                us4 pk = { f2bf(acc[mt][nt][0]), f2bf(acc[mt][nt][1]),
                           f2bf(acc[mt][nt][2]), f2bf(acc[mt][nt][3]) };
                *(us4*)(vtbf + ((size_t)(bb * 512 + d)) * 2048 + nn) = pk;
            }
        }
    }
}

// ---------------------------------------------------------------------------
// score body: S = Q@K^T (128x128 tile), P = exp(S*scale) -> bf16, l atomics.
// ---------------------------------------------------------------------------
__device__ __forceinline__ void score_body(
    const unsigned short* __restrict__ qbf, const unsigned short* __restrict__ kbf,
    unsigned short* __restrict__ pbf, float* __restrict__ lg,
    int b, int m0, int n0, int t, unsigned short* As, unsigned short* Bs)
{
    f32x4 acc[4][4] = {};
    gemm_core128(qbf + (size_t)(b * 2048 + m0) * 512, 512,
                 kbf + (size_t)(b * 2048 + n0) * 512, 512,
                 512, As, Bs, t, acc);

    int wave = t >> 6, lane = t & 63, c = lane & 15, quad = lane >> 4;
    int wm = (wave >> 1) * 64, wn = (wave & 1) * 64;
    const float scale = 0.044194173824159216f;    // 1/sqrt(512)

    #pragma unroll
    for (int mt = 0; mt < 4; mt++) {
        #pragma unroll
        for (int r = 0; r < 4; r++) {
            int row = m0 + wm + mt * 16 + quad * 4 + r;
            float rs = 0.f;
            #pragma unroll
            for (int nt = 0; nt < 4; nt++) {
                float p = __expf(acc[mt][nt][r] * scale);
                rs += p;
                pbf[(size_t)(b * 2048 + row) * 2048 + n0 + wn + nt * 16 + c] = f2bf(p);
            }
            rs += __shfl_xor(rs, 1, 16);
            rs += __shfl_xor(rs, 2, 16);
            rs += __shfl_xor(rs, 4, 16);
            rs += __shfl_xor(rs, 8, 16);
            if (c == 0) atomicAdd(&lg[b * 2048 + row], rs);
        }
    }
}

// ---------------------------------------------------------------------------
// prior body: one block per (b,i) row. sigma = x_row.Ws; row-normalized
// gaussian (inv_norm prefactor cancels). Vectorized float4 stores.
// ---------------------------------------------------------------------------
__device__ __forceinline__ void prior_body(
    const float* __restrict__ x, const float* __restrict__ wsv,
    float* __restrict__ pout, int blk, int t, float* red, float* red2)
{
    int i = blk & 2047;
    const float* xr = x + (size_t)blk * 512;

    float part = xr[t] * wsv[t] + xr[t + 256] * wsv[t + 256];
    #pragma unroll
    for (int o = 32; o; o >>= 1) part += __shfl_xor(part, o, 64);
    if ((t & 63) == 0) red[t >> 6] = part;
    __syncthreads();
    float sigma = red[0] + red[1] + red[2] + red[3];

    float inv2 = 0.5f / (sigma * sigma);
    float g[8];
    float sum = 0.f;
    int j0 = t * 8;                      // 8 contiguous columns per thread
    #pragma unroll
    for (int u = 0; u < 8; u++) {
        int j = j0 + u;
        float d = (float)(j - i);
        g[u] = (j == i) ? 1.0f : __expf(-(d * d) * inv2);
        sum += g[u];
    }
    #pragma unroll
    for (int o = 32; o; o >>= 1) sum += __shfl_xor(sum, o, 64);
    if ((t & 63) == 0) red2[t >> 6] = sum;
    __syncthreads();
    float inv = 1.0f / (red2[0] + red2[1] + red2[2] + red2[3]);

    float* pr = pout + (size_t)blk * 2048 + j0;
    float4 o0 = { g[0] * inv, g[1] * inv, g[2] * inv, g[3] * inv };
    float4 o1 = { g[4] * inv, g[5] * inv, g[6] * inv, g[7] * inv };
    ((float4*)pr)[0] = o0;
    ((float4*)pr)[1] = o1;
}

// ---------------------------------------------------------------------------
// Kernel 3a (ws path): merged score + prior. Grid 9216 1D:
// blocks [0,1024) score (b = bid>>8, m-tile = bid&15, n-tile = (bid>>4)&15),
// blocks [1024,9216) prior row bid-1024. Prior writes overlap score compute
// (pout is disjoint from all scratch when scratch lives in d_ws).
// ---------------------------------------------------------------------------
__global__ __launch_bounds__(256) void k_score_prior(
    const unsigned short* __restrict__ qbf, const unsigned short* __restrict__ kbf,
    unsigned short* __restrict__ pbf, float* __restrict__ lg,
    const float* __restrict__ x, const float* __restrict__ wsv,
    float* __restrict__ pout)
{
    __shared__ __align__(16) unsigned short As[128 * 32];
    __shared__ __align__(16) unsigned short Bs[128 * 32];
    __shared__ float red[4];
    __shared__ float red2[4];

    int bid = blockIdx.x, t = threadIdx.x;
    if (bid < 1024) {
        int b = bid >> 8, r = bid & 255;
        score_body(qbf, kbf, pbf, lg, b, (r & 15) * 128, (r >> 4) * 128, t, As, Bs);
    } else {
        prior_body(x, wsv, pout, bid - 1024, t, red, red2);
    }
}

// ---------------------------------------------------------------------------
// Kernel 3b (fallback): standalone score. Grid (16,16,4).
// ---------------------------------------------------------------------------
__global__ __launch_bounds__(256) void k_score(
    const unsigned short* __restrict__ qbf, const unsigned short* __restrict__ kbf,
    unsigned short* __restrict__ pbf, float* __restrict__ lg)
{
    __shared__ __align__(16) unsigned short As[128 * 32];
    __shared__ __align__(16) unsigned short Bs[128 * 32];
    score_body(qbf, kbf, pbf, lg, blockIdx.z,
               blockIdx.x * 128, blockIdx.y * 128, threadIdx.x, As, Bs);
}

// ---------------------------------------------------------------------------
// Kernel 4: output. Per batch: O = P @ Vt^T scaled by 1/l. 128x64 tile,
// grid (16,8,4) = 512 blocks (2 blocks/CU — fixes round-3's 1 block/CU).
// Wave quadrants 2x2 of 64x32: acc[4][2], per iter 3 staging + 6 ds_read +
// 8 MFMA, K=2048 -> 64 iters.
// ---------------------------------------------------------------------------
__global__ __launch_bounds__(256) void k_out(
    const unsigned short* __restrict__ pbf, const unsigned short* __restrict__ vtbf,
    const float* __restrict__ lg, float* __restrict__ zout)
{
    __shared__ __align__(16) unsigned short As[128 * 32];   // P tile
    __shared__ __align__(16) unsigned short Bs[64 * 32];    // Vt tile
    __shared__ float invl[128];

    int t = threadIdx.x;
    int b = blockIdx.z;
    int m0 = blockIdx.x * 128, n0 = blockIdx.y * 64;

    if (t < 128) invl[t] = 1.0f / lg[b * 2048 + m0 + t];

    const unsigned short* Ab = pbf + (size_t)(b * 2048 + m0) * 2048;
    const unsigned short* Bb = vtbf + (size_t)(b * 512 + n0) * 2048;

    const int wave = t >> 6, lane = t & 63;
    const int c = lane & 15, quad = lane >> 4;
    const int wm = (wave >> 1) * 64, wn = (wave & 1) * 32;
    const int srow = t >> 2;
    const int scol = (t & 3) * 8;

    f32x4 acc[4][2] = {};

    for (int k0 = 0; k0 < 2048; k0 += 32) {
        __syncthreads();
        const unsigned short* ga = Ab + (size_t)srow * 2048 + k0 + scol;
        GLOAD_LDS16(ga,             As + t * 8);
        GLOAD_LDS16(ga + 64 * 2048, As + 2048 + t * 8);
        GLOAD_LDS16(Bb + (size_t)srow * 2048 + k0 + scol, Bs + t * 8);
        __syncthreads();

        s16x8 af[4], bf[2];
        #pragma unroll
        for (int i = 0; i < 4; i++)
            af[i] = *(const s16x8*)(As + (wm + i * 16 + c) * 32 + quad * 8);
        #pragma unroll
        for (int i = 0; i < 2; i++)
            bf[i] = *(const s16x8*)(Bs + (wn + i * 16 + c) * 32 + quad * 8);
        #pragma unroll
        for (int mt = 0; mt < 4; mt++)
            #pragma unroll
            for (int nt = 0; nt < 2; nt++)
                acc[mt][nt] = MFMA16(af[mt], bf[nt], acc[mt][nt]);
    }

    #pragma unroll
    for (int mt = 0; mt < 4; mt++) {
        #pragma unroll
        for (int nt = 0; nt < 2; nt++) {
            #pragma unroll
            for (int r = 0; r < 4; r++) {
                int row = wm + mt * 16 + quad * 4 + r;
                zout[(size_t)(b * 2048 + m0 + row) * 512 + n0 + wn + nt * 16 + c]
                    = acc[mt][nt][r] * invl[row];
            }
        }
    }
}

// ---------------------------------------------------------------------------
// Kernel 5 (fallback): standalone prior. Grid 8192.
// ---------------------------------------------------------------------------
__global__ __launch_bounds__(256) void k_prior(
    const float* __restrict__ x, const float* __restrict__ wsv,
    float* __restrict__ pout)
{
    __shared__ float red[4];
    __shared__ float red2[4];
    prior_body(x, wsv, pout, blockIdx.x, threadIdx.x, red, red2);
}

// ---------------------------------------------------------------------------
extern "C" void kernel_launch(void* const* d_in, const int* in_sizes, int n_in,
                              void* d_out, int out_size, void* d_ws, size_t ws_size,
                              hipStream_t stream)
{
    const float* x  = (const float*)d_in[0];
    const float* wq = (const float*)d_in[1];
    const float* wk = (const float*)d_in[2];
    const float* wv = (const float*)d_in[3];
    const float* ws = (const float*)d_in[4];

    float* zout = (float*)d_out;                       // (4,2048,512)
    float* pout = zout + (size_t)4 * 2048 * 512;       // (4,2048,2048) = 67.1 MB

    // Scratch needs: xbf 4.19M + wt 0.79M + q/k/vt 3*4.19M + pbf 16.78M
    // ushorts + lg 8192 f32 = 68.7 MB.
    const size_t need = ((size_t)4194304 + 786432 + 3 * 4194304 + 16777216) * 2
                        + 8192 * 4;

    if (ws_size >= need) {
        // ---- ws path: all scratch in d_ws; pout free -> prior overlaps score
        unsigned short* base = (unsigned short*)d_ws;
        unsigned short* xbf  = base;
        unsigned short* wt   = xbf  + (size_t)4194304;
        unsigned short* qbf  = wt   + (size_t)786432;
        unsigned short* kbf  = qbf  + (size_t)4194304;
        unsigned short* vtbf = kbf  + (size_t)4194304;
        unsigned short* pbf  = vtbf + (size_t)4194304;
        float*          lg   = (float*)(pbf + (size_t)16777216);

        k_convert<<<dim3(7200), dim3(256), 0, stream>>>(x, wq, wk, wv, xbf, wt, lg);
        k_proj       <<<dim3(64, 12),   dim3(256), 0, stream>>>(xbf, wt, qbf, kbf, vtbf);
        k_score_prior<<<dim3(9216),     dim3(256), 0, stream>>>(qbf, kbf, pbf, lg, x, ws, pout);
        k_out        <<<dim3(16, 8, 4), dim3(256), 0, stream>>>(pbf, vtbf, lg, zout);
    } else {
        // ---- fallback: round-3 layout inside pout (prior runs last)
        unsigned short* base = (unsigned short*)pout;
        unsigned short* pbf  = base;                        // 16,777,216
        unsigned short* qbf  = base + (size_t)16777216;
        unsigned short* kbf  = qbf  + (size_t)4194304;
        unsigned short* vtbf = kbf  + (size_t)4194304;
        float*          lg   = (float*)(vtbf + (size_t)4194304);
        unsigned short* xbf  = base;                        // overlaps pbf (ok)
        unsigned short* wt   = base + (size_t)4194304;      // overlaps pbf (ok)

        k_convert<<<dim3(7200), dim3(256), 0, stream>>>(x, wq, wk, wv, xbf, wt, lg);
        k_proj  <<<dim3(64, 12),    dim3(256), 0, stream>>>(xbf, wt, qbf, kbf, vtbf);
        k_score <<<dim3(16, 16, 4), dim3(256), 0, stream>>>(qbf, kbf, pbf, lg);
        k_out   <<<dim3(16, 8, 4),  dim3(256), 0, stream>>>(pbf, vtbf, lg, zout);
        k_prior <<<dim3(8192),      dim3(256), 0, stream>>>(x, ws, pout);
    }
}